// Round 8
// baseline (824.312 us; speedup 1.0000x reference)
//
#include <hip/hip_runtime.h>
#include <hip/hip_bf16.h>
#include <math.h>

// ---------------- problem constants ----------------
#define N_RAYS 4096
#define N_SAMPLES 64
#define M_TOTAL (N_RAYS * N_SAMPLES)   // 262144 points
#define MTILE 64                       // points per block (1 ray)
#define NBLK (M_TOTAL / MTILE)         // 4096 blocks
#define THREADS 512                    // 8 waves

// packed bf16 weight offsets in workspace (elements)
#define OFF_W0 0        // [256][64]   (63 -> pad 64)
#define OFF_W1 16384    // [256][256]
#define OFF_W2 81920
#define OFF_W3 147456
#define OFF_W4 212992   // [256][320]  (319 -> pad 320)
#define OFF_W5 294912
#define OFF_W6 360448
#define OFF_W7 425984
#define OFF_WF 491520   // feat [256][256]
#define OFF_WD 557056   // dir  [128][288] (283 -> pad 288)

typedef __attribute__((ext_vector_type(8))) short bf16x8;
typedef __attribute__((ext_vector_type(4))) float f32x4;
typedef __attribute__((ext_vector_type(4))) unsigned short u16x4;

__device__ __forceinline__ unsigned short f2bf(float f) {
  union { float f; unsigned u; } v; v.f = f;
  unsigned r = v.u + 0x7FFFu + ((v.u >> 16) & 1u);   // RNE
  return (unsigned short)(r >> 16);
}
__device__ __forceinline__ float bf2f(unsigned short h) {
  union { unsigned u; float f; } v; v.u = ((unsigned)h) << 16;
  return v.f;
}

// Swizzled LDS element index. f(row) = (row&7) ^ ((row>>3)&1): bijective on any
// 8 consecutive rows -> b128 reads across 8/16 consecutive rows hit distinct
// bank octets. Swizzle applies only below SWL (region must be 64-col aligned).
// XOR operates on 8-element groups, so 4-element-aligned accesses (b64 writes)
// and 8-element-aligned accesses (b128 reads) stay contiguous.
template<int STRIDE, int SWL>
__device__ __forceinline__ int sidx(int r, int c) {
  const int f = (r & 7) ^ ((r >> 3) & 1);
  const int cc = (c < SWL) ? (c ^ (f << 3)) : c;
  return r * STRIDE + cc;
}

// One fused MLP layer: out[64][N] = relu(act[64][K] * W^T + b), bf16 MFMA.
// TRANSPOSED product: acc = mfma(A=W_frag, B=act_frag) so D = [feature][point]:
// D col (lane&15) = point, D rows ((lane>>4)*4+r) = 4 CONSECUTIVE features.
// Epilogue is then one 8-byte ds_write_b64 per frag (bank-uniform, vs the old
// 4x-conflicted per-element b16 writes that cost ~27% of kernel cycles).
// Per wave: 4 point-frags x NF feature-frags; 8 waves cover N = NF*16*8 cols.
template<int KPAD, int NF, int SI, int SWLI, int SO, int SWLO>
__device__ __forceinline__ void layer_mfma(
    const unsigned short* __restrict__ inb, int col0,
    unsigned short* __restrict__ outb,
    const unsigned short* __restrict__ W,   // packed bf16 [Nout][KPAD]
    const float* __restrict__ bias,
    int wave, int ln15, int lhi)
{
  f32x4 acc[4][NF];
#pragma unroll
  for (int m = 0; m < 4; ++m)
#pragma unroll
    for (int n = 0; n < NF; ++n)
      acc[m][n] = (f32x4){0.f, 0.f, 0.f, 0.f};

  const unsigned short* wr[NF];
#pragma unroll
  for (int n = 0; n < NF; ++n)
    wr[n] = W + (wave * (NF * 16) + n * 16 + ln15) * KPAD + lhi * 8;

  const int kb = col0 + lhi * 8;
#pragma unroll
  for (int k0 = 0; k0 < KPAD; k0 += 32) {
    bf16x8 w[NF];
#pragma unroll
    for (int n = 0; n < NF; ++n)
      w[n] = *(const bf16x8*)(wr[n] + k0);
    bf16x8 a[4];
#pragma unroll
    for (int m = 0; m < 4; ++m)
      a[m] = *(const bf16x8*)(inb + sidx<SI, SWLI>(m * 16 + ln15, kb + k0));
#pragma unroll
    for (int n = 0; n < NF; ++n)
#pragma unroll
      for (int m = 0; m < 4; ++m)
        acc[m][n] = __builtin_amdgcn_mfma_f32_16x16x32_bf16(w[n], a[m], acc[m][n], 0, 0, 0);
  }

  // epilogue: +bias, relu, f32->bf16, b64 write of 4 consecutive features
#pragma unroll
  for (int n = 0; n < NF; ++n) {
    const int feat0 = wave * (NF * 16) + n * 16 + lhi * 4;
    const f32x4 bb = *(const f32x4*)(bias + feat0);
#pragma unroll
    for (int m = 0; m < 4; ++m) {
      u16x4 pk;
#pragma unroll
      for (int r = 0; r < 4; ++r) {
        float v = acc[m][n][r] + bb[r];
        pk[r] = f2bf(fmaxf(v, 0.f));
      }
      *(u16x4*)(outb + sidx<SO, SWLO>(m * 16 + ln15, feat0)) = pk;
    }
  }
}

struct NerfArgs {
  const float *sp, *dirs;
  const unsigned short* wp;
  const float *bx0, *bx1, *bx2, *bx3, *bx4, *bx5, *bx6, *bx7;
  const float *bd0, *Wden, *bden, *bfeat, *Wrgb, *brgb;
  float* out;
};

// 76 KB LDS -> 2 blocks/CU (4 waves/SIMD). Pin waves_per_eu=4 -> VGPR<=128,
// working set ~96 VGPRs (acc 32 + frags 24 + addr) -> no spills.
__global__ void __attribute__((amdgpu_flat_work_group_size(THREADS, THREADS),
                               amdgpu_waves_per_eu(4, 4)))
nerf_main(NerfArgs A) {
  extern __shared__ unsigned short lds[];
  unsigned short* buf0 = lds;              // [64][320]: cols 256..319 emb_x, later emb_d stage
  unsigned short* buf1 = lds + 64 * 320;   // [64][288]: cols 256..287 emb_d (late)
  const int tid = threadIdx.x;
  const int wave = tid >> 6, lane = tid & 63;
  const int ln15 = lane & 15, lhi = lane >> 4;
  const int blk = blockIdx.x;

  // ---- harmonic(sample_points) -> buf0 cols [256..320)
  {
    const int r = tid & 63, g = tid >> 6;   // g = wave
    if (g < 3) {
      const float x = A.sp[(blk * MTILE + r) * 3 + g];
      buf0[sidx<320, 320>(r, 256 + 60 + g)] = f2bf(x);
#pragma unroll
      for (int f = 0; f < 10; ++f) {
        const float ar = x * (float)(1 << f);
        buf0[sidx<320, 320>(r, 256 + g * 10 + f)]      = f2bf(sinf(ar));
        buf0[sidx<320, 320>(r, 256 + 30 + g * 10 + f)] = f2bf(cosf(ar));
      }
    } else if (g == 3) {
      buf0[sidx<320, 320>(r, 319)] = 0;  // zero pad col (L4's k=319)
    }
  }
  __syncthreads();

  const unsigned short* wp = A.wp;
  // xyz MLP: L0 reads emb (buf0 cols 256+), then ping-pong buf1<->buf0
  layer_mfma<64, 2, 320, 320, 288, 256>(buf0, 256, buf1, wp + OFF_W0, A.bx0, wave, ln15, lhi);
  __syncthreads();
  layer_mfma<256, 2, 288, 256, 320, 320>(buf1, 0, buf0, wp + OFF_W1, A.bx1, wave, ln15, lhi);
  __syncthreads();
  layer_mfma<256, 2, 320, 320, 288, 256>(buf0, 0, buf1, wp + OFF_W2, A.bx2, wave, ln15, lhi);
  __syncthreads();
  layer_mfma<256, 2, 288, 256, 320, 320>(buf1, 0, buf0, wp + OFF_W3, A.bx3, wave, ln15, lhi);
  __syncthreads();
  // L4: skip concat [act3, emb_x] = buf0 cols [0..320)
  layer_mfma<320, 2, 320, 320, 288, 256>(buf0, 0, buf1, wp + OFF_W4, A.bx4, wave, ln15, lhi);
  __syncthreads();
  layer_mfma<256, 2, 288, 256, 320, 320>(buf1, 0, buf0, wp + OFF_W5, A.bx5, wave, ln15, lhi);
  __syncthreads();
  layer_mfma<256, 2, 320, 320, 288, 256>(buf0, 0, buf1, wp + OFF_W6, A.bx6, wave, ln15, lhi);
  __syncthreads();
  layer_mfma<256, 2, 288, 256, 320, 320>(buf1, 0, buf0, wp + OFF_W7, A.bx7, wave, ln15, lhi);
  __syncthreads();
  // feat: buf0(act7) -> buf1 cols [0..256)
  layer_mfma<256, 2, 320, 320, 288, 256>(buf0, 0, buf1, wp + OFF_WF, A.bfeat, wave, ln15, lhi);

  // density head: relu(act7 . Wden + bden), act7 in buf0 cols [0..256).
  // Waves 0..3 own the 64 points; result kept in-register until the rgb store.
  float dens = 0.f;
  if (wave < 4) {
    const int r = wave * 16 + ln15;
    float s = 0.f;
#pragma unroll
    for (int jj = 0; jj < 8; ++jj) {
      const bf16x8 ch = *(const bf16x8*)(buf0 + sidx<320, 320>(r, lhi * 64 + jj * 8));
#pragma unroll
      for (int e = 0; e < 8; ++e)
        s += bf2f((unsigned short)ch[e]) * A.Wden[lhi * 64 + jj * 8 + e];
    }
    s += __shfl_xor(s, 16);
    s += __shfl_xor(s, 32);
    dens = fmaxf(s + A.bden[0], 0.f);
  }
  // stage harmonic(direction) for this block's single ray -> buf0 row 0, cols [288..320)
  // (emb_x region of buf0 is dead after L4; feat reads cols [0..256) only)
  if (tid < 32) {
    const int j = tid;
    const float* dp = A.dirs + blk * 3;
    float val = 0.f;
    if (j < 12)      { int d = j >> 2, f = j & 3;               val = sinf(dp[d] * (float)(1 << f)); }
    else if (j < 24) { int d = (j - 12) >> 2, f = (j - 12) & 3; val = cosf(dp[d] * (float)(1 << f)); }
    else if (j < 27) { val = dp[j - 24]; }
    buf0[sidx<320, 320>(0, 288 + j)] = f2bf(val);  // j=27..31 -> zero pad
  }
  __syncthreads();
  // broadcast emb_d to all 64 rows of buf1 cols [256..288)
  for (int idx = tid; idx < 64 * 32; idx += THREADS) {
    const int rr = idx >> 5, cc = idx & 31;
    buf1[sidx<288, 256>(rr, 256 + cc)] = buf0[sidx<320, 320>(0, 288 + cc)];
  }
  __syncthreads();
  // dir layer: [feat, emb_d] (buf1, K=288) -> buf0 cols [0..128)
  layer_mfma<288, 1, 288, 256, 320, 320>(buf1, 0, buf0, wp + OFF_WD, A.bd0, wave, ln15, lhi);
  __syncthreads();
  // rgb head: sigmoid(x_dir . Wrgb^T + brgb); fused float4 {dens, rgb} store
  if (wave < 4) {
    const int r = wave * 16 + ln15;
    float s0 = 0.f, s1 = 0.f, s2 = 0.f;
#pragma unroll
    for (int jj = 0; jj < 4; ++jj) {
      const bf16x8 ch = *(const bf16x8*)(buf0 + sidx<320, 320>(r, lhi * 32 + jj * 8));
#pragma unroll
      for (int e = 0; e < 8; ++e) {
        const int k = lhi * 32 + jj * 8 + e;
        const float xv = bf2f((unsigned short)ch[e]);
        s0 += xv * A.Wrgb[k];
        s1 += xv * A.Wrgb[128 + k];
        s2 += xv * A.Wrgb[256 + k];
      }
    }
    s0 += __shfl_xor(s0, 16); s0 += __shfl_xor(s0, 32);
    s1 += __shfl_xor(s1, 16); s1 += __shfl_xor(s1, 32);
    s2 += __shfl_xor(s2, 16); s2 += __shfl_xor(s2, 32);
    if (lhi == 0) {
      f32x4 o;
      o[0] = dens;
      o[1] = 1.f / (1.f + expf(-(s0 + A.brgb[0])));
      o[2] = 1.f / (1.f + expf(-(s1 + A.brgb[1])));
      o[3] = 1.f / (1.f + expf(-(s2 + A.brgb[2])));
      *(f32x4*)(A.out + (blk * MTILE + r) * 4) = o;
    }
  }
}

// ---------------- weight packing prologue (fp32 -> bf16, K padded) ----------------
struct PackDesc { const float* src; int out_dim, in_dim, kpad, dst_off; };
struct PackArgs { PackDesc d[10]; };

__global__ void __launch_bounds__(256) pack_weights(PackArgs P, unsigned short* dst) {
  const PackDesc pd = P.d[blockIdx.y];
  const int idx = blockIdx.x * 256 + threadIdx.x;
  const int tot = pd.out_dim * pd.kpad;
  if (idx >= tot) return;
  const int o = idx / pd.kpad;
  const int k = idx - o * pd.kpad;
  const float v = (k < pd.in_dim) ? pd.src[o * pd.in_dim + k] : 0.f;
  dst[pd.dst_off + idx] = f2bf(v);
}

extern "C" void kernel_launch(void* const* d_in, const int* in_sizes, int n_in,
                              void* d_out, int out_size, void* d_ws, size_t ws_size,
                              hipStream_t stream) {
  unsigned short* wpack = (unsigned short*)d_ws;

  const float* Wx[8]; const float* bx[8];
  for (int i = 0; i < 8; ++i) {
    Wx[i] = (const float*)d_in[2 + 2 * i];
    bx[i] = (const float*)d_in[3 + 2 * i];
  }

  PackArgs P;
  P.d[0] = { Wx[0], 256, 63, 64, OFF_W0 };
  P.d[1] = { Wx[1], 256, 256, 256, OFF_W1 };
  P.d[2] = { Wx[2], 256, 256, 256, OFF_W2 };
  P.d[3] = { Wx[3], 256, 256, 256, OFF_W3 };
  P.d[4] = { Wx[4], 256, 319, 320, OFF_W4 };
  P.d[5] = { Wx[5], 256, 256, 256, OFF_W5 };
  P.d[6] = { Wx[6], 256, 256, 256, OFF_W6 };
  P.d[7] = { Wx[7], 256, 256, 256, OFF_W7 };
  P.d[8] = { (const float*)d_in[22], 256, 256, 256, OFF_WF };  // Wfeat
  P.d[9] = { (const float*)d_in[18], 128, 283, 288, OFF_WD };  // Wd0
  hipLaunchKernelGGL(pack_weights, dim3(320, 10), dim3(256), 0, stream, P, wpack);

  NerfArgs A;
  A.sp = (const float*)d_in[0];
  A.dirs = (const float*)d_in[1];
  A.wp = wpack;
  A.bx0 = bx[0]; A.bx1 = bx[1]; A.bx2 = bx[2]; A.bx3 = bx[3];
  A.bx4 = bx[4]; A.bx5 = bx[5]; A.bx6 = bx[6]; A.bx7 = bx[7];
  A.bd0 = (const float*)d_in[19];
  A.Wden = (const float*)d_in[20];
  A.bden = (const float*)d_in[21];
  A.bfeat = (const float*)d_in[23];
  A.Wrgb = (const float*)d_in[24];
  A.brgb = (const float*)d_in[25];
  A.out = (float*)d_out;

  const int lds_bytes = (64 * 320 + 64 * 288) * 2;  // 77824 B -> 2 blocks/CU
  hipFuncSetAttribute((const void*)nerf_main, hipFuncAttributeMaxDynamicSharedMemorySize, lds_bytes);
  hipLaunchKernelGGL(nerf_main, dim3(NBLK), dim3(THREADS), lds_bytes, stream, A);
}

// Round 9
// 481.827 us; speedup vs baseline: 1.7108x; 1.7108x over previous
//
#include <hip/hip_runtime.h>
#include <hip/hip_bf16.h>
#include <math.h>

// ---------------- problem constants ----------------
#define N_RAYS 4096
#define N_SAMPLES 64
#define M_TOTAL (N_RAYS * N_SAMPLES)   // 262144 points
#define MTILE 128                      // points per block (2 rays)
#define NBLK (M_TOTAL / MTILE)         // 2048 blocks
#define THREADS 512                    // 8 waves

// packed bf16 weight offsets in workspace (elements)
#define OFF_W0 0        // [256][64]   (63 -> pad 64)
#define OFF_W1 16384    // [256][256]
#define OFF_W2 81920
#define OFF_W3 147456
#define OFF_W4 212992   // [256][320]  (319 -> pad 320)
#define OFF_W5 294912
#define OFF_W6 360448
#define OFF_W7 425984
#define OFF_WF 491520   // feat [256][256]
#define OFF_WD 557056   // dir  [128][288] (283 -> pad 288)

typedef __attribute__((ext_vector_type(8))) short bf16x8;
typedef __attribute__((ext_vector_type(4))) float f32x4;
typedef __attribute__((ext_vector_type(4))) unsigned short u16x4;

__device__ __forceinline__ unsigned short f2bf(float f) {
  __hip_bfloat16 h = __float2bfloat16(f);   // HW RNE convert
  return *(unsigned short*)&h;
}
__device__ __forceinline__ float bf2f(unsigned short h) {
  union { unsigned u; float f; } v; v.u = ((unsigned)h) << 16;
  return v.f;
}

// Swizzled LDS element index, f(row) = row&7 (R2's original — measured 3.25e7
// conflict cycles vs 8.47e7 for the R3 variant; the R3 "fix" was a regression:
// its 4 distinct-f epilogue groups hit 16 banks with distinct dwords = 4-way,
// while row&7's duplicate f pairs merge into the same dword = ~2-way).
// XOR granule is 8 elements: b128 reads (8-aligned) and b64 writes (4-aligned)
// stay contiguous. Swizzle applies only below SWL (64-col-aligned region).
template<int STRIDE, int SWL>
__device__ __forceinline__ int sidx(int r, int c) {
  const int cc = (c < SWL) ? (c ^ ((r & 7) << 3)) : c;
  return r * STRIDE + cc;
}

// One fused MLP layer: out[128][N] = relu(act[128][K] * W^T + b), bf16 MFMA.
// TRANSPOSED product (verified R8): acc = mfma(A=W_frag, B=act_frag) so
// D = [feature][point]: col (lane&15) = point, rows ((lane>>4)*4+r) = 4
// CONSECUTIVE features -> epilogue is one 8-byte ds_write_b64 per frag
// (bank-uniform) instead of 4 conflicted b16 writes.
// Per wave: 8 point-frags x NF feature-frags; 8 waves cover NF*16*8 features.
template<int KPAD, int NF, int SI, int SWLI, int SO, int SWLO>
__device__ __forceinline__ void layer_mfma(
    const unsigned short* __restrict__ inb, int col0,
    unsigned short* __restrict__ outb,
    const unsigned short* __restrict__ W,   // packed bf16 [Nout][KPAD]
    const float* __restrict__ bias,
    int wave, int ln15, int lhi)
{
  f32x4 acc[8][NF];
#pragma unroll
  for (int m = 0; m < 8; ++m)
#pragma unroll
    for (int n = 0; n < NF; ++n)
      acc[m][n] = (f32x4){0.f, 0.f, 0.f, 0.f};

  const unsigned short* wr[NF];
#pragma unroll
  for (int n = 0; n < NF; ++n)
    wr[n] = W + (wave * (NF * 16) + n * 16 + ln15) * KPAD + lhi * 8;

  const int kb = col0 + lhi * 8;
#pragma unroll
  for (int k0 = 0; k0 < KPAD; k0 += 32) {
    bf16x8 w[NF];
#pragma unroll
    for (int n = 0; n < NF; ++n)
      w[n] = *(const bf16x8*)(wr[n] + k0);
#pragma unroll
    for (int g = 0; g < 2; ++g) {
      bf16x8 a[4];
#pragma unroll
      for (int mm = 0; mm < 4; ++mm)
        a[mm] = *(const bf16x8*)(inb + sidx<SI, SWLI>((g * 4 + mm) * 16 + ln15, kb + k0));
#pragma unroll
      for (int n = 0; n < NF; ++n)
#pragma unroll
        for (int mm = 0; mm < 4; ++mm)
          acc[g * 4 + mm][n] =
              __builtin_amdgcn_mfma_f32_16x16x32_bf16(w[n], a[mm], acc[g * 4 + mm][n], 0, 0, 0);
    }
  }

  // epilogue: +bias, relu, f32->bf16, b64 write of 4 consecutive features
#pragma unroll
  for (int n = 0; n < NF; ++n) {
    const int feat0 = wave * (NF * 16) + n * 16 + lhi * 4;
    const f32x4 bb = *(const f32x4*)(bias + feat0);
#pragma unroll
    for (int m = 0; m < 8; ++m) {
      u16x4 pk;
#pragma unroll
      for (int r = 0; r < 4; ++r)
        pk[r] = f2bf(fmaxf(acc[m][n][r] + bb[r], 0.f));
      *(u16x4*)(outb + sidx<SO, SWLO>(m * 16 + ln15, feat0)) = pk;
    }
  }
}

struct NerfArgs {
  const float *sp, *dirs;
  const unsigned short* wp;
  const float *bx0, *bx1, *bx2, *bx3, *bx4, *bx5, *bx6, *bx7;
  const float *bd0, *Wden, *bden, *bfeat, *Wrgb, *brgb;
  float* out;
};

// Pin exactly 2 waves/EU (the LDS-capped occupancy we get anyway) so the
// register allocator uses the full budget. (waves_per_eu(4,4) in R8 cut the
// budget to 64 arch VGPRs -> 798 MB of spill traffic. Do not raise this.)
__global__ void __attribute__((amdgpu_flat_work_group_size(THREADS, THREADS),
                               amdgpu_waves_per_eu(2, 2)))
nerf_main(NerfArgs A) {
  extern __shared__ unsigned short lds[];
  unsigned short* buf0 = lds;               // [128][320]: cols 256..319 hold emb_x
  unsigned short* buf1 = lds + 128 * 320;   // [128][288]: cols 256..287 hold emb_d (late)
  const int tid = threadIdx.x;
  const int wave = tid >> 6, lane = tid & 63;
  const int ln15 = lane & 15, lhi = lane >> 4;
  const int blk = blockIdx.x;

  // ---- harmonic(sample_points) -> buf0 cols [256..320)
  {
    const int r = tid & 127, g = tid >> 7;
    if (g < 3) {
      const float x = A.sp[(blk * MTILE + r) * 3 + g];
      buf0[sidx<320, 320>(r, 256 + 60 + g)] = f2bf(x);
#pragma unroll
      for (int f = 0; f < 10; ++f) {
        const float ar = x * (float)(1 << f);
        buf0[sidx<320, 320>(r, 256 + g * 10 + f)]      = f2bf(sinf(ar));
        buf0[sidx<320, 320>(r, 256 + 30 + g * 10 + f)] = f2bf(cosf(ar));
      }
    } else {
      buf0[sidx<320, 320>(r, 319)] = 0;  // zero pad col (L4's k=319)
    }
  }
  __syncthreads();

  const unsigned short* wp = A.wp;
  // xyz MLP: L0 reads emb (buf0 cols 256+), then ping-pong buf1<->buf0
  layer_mfma<64, 2, 320, 320, 288, 256>(buf0, 256, buf1, wp + OFF_W0, A.bx0, wave, ln15, lhi);
  __syncthreads();
  layer_mfma<256, 2, 288, 256, 320, 320>(buf1, 0, buf0, wp + OFF_W1, A.bx1, wave, ln15, lhi);
  __syncthreads();
  layer_mfma<256, 2, 320, 320, 288, 256>(buf0, 0, buf1, wp + OFF_W2, A.bx2, wave, ln15, lhi);
  __syncthreads();
  layer_mfma<256, 2, 288, 256, 320, 320>(buf1, 0, buf0, wp + OFF_W3, A.bx3, wave, ln15, lhi);
  __syncthreads();
  // L4: skip concat [act3, emb_x] = buf0 cols [0..320)
  layer_mfma<320, 2, 320, 320, 288, 256>(buf0, 0, buf1, wp + OFF_W4, A.bx4, wave, ln15, lhi);
  __syncthreads();
  layer_mfma<256, 2, 288, 256, 320, 320>(buf1, 0, buf0, wp + OFF_W5, A.bx5, wave, ln15, lhi);
  __syncthreads();
  layer_mfma<256, 2, 320, 320, 288, 256>(buf0, 0, buf1, wp + OFF_W6, A.bx6, wave, ln15, lhi);
  __syncthreads();
  layer_mfma<256, 2, 288, 256, 320, 320>(buf1, 0, buf0, wp + OFF_W7, A.bx7, wave, ln15, lhi);
  __syncthreads();
  // feat: buf0(act7) -> buf1 cols [0..256)
  layer_mfma<256, 2, 320, 320, 288, 256>(buf0, 0, buf1, wp + OFF_WF, A.bfeat, wave, ln15, lhi);

  // density head: relu(act7 . Wden + bden), act7 in buf0 cols [0..256).
  // 8 waves x 16 rows; lhi owns a 64-col quarter; kept in-register to the end.
  float dens = 0.f;
  {
    const int r = wave * 16 + ln15;
    float s = 0.f;
#pragma unroll
    for (int jj = 0; jj < 8; ++jj) {
      const bf16x8 ch = *(const bf16x8*)(buf0 + sidx<320, 320>(r, lhi * 64 + jj * 8));
#pragma unroll
      for (int e = 0; e < 8; ++e)
        s += bf2f((unsigned short)ch[e]) * A.Wden[lhi * 64 + jj * 8 + e];
    }
    s += __shfl_xor(s, 16);
    s += __shfl_xor(s, 32);
    dens = fmaxf(s + A.bden[0], 0.f);
  }
  // stage harmonic(direction) per ray into buf0 rows 0/1, cols [288..320)
  if (tid < 64) {
    const int j = tid & 31, h = tid >> 5;  // h: which of the 2 rays in this tile
    const float* dp = A.dirs + (blk * 2 + h) * 3;
    float val = 0.f;
    if (j < 12)      { int d = j >> 2, f = j & 3;               val = sinf(dp[d] * (float)(1 << f)); }
    else if (j < 24) { int d = (j - 12) >> 2, f = (j - 12) & 3; val = cosf(dp[d] * (float)(1 << f)); }
    else if (j < 27) { val = dp[j - 24]; }
    buf0[sidx<320, 320>(h, 288 + j)] = f2bf(val);  // j=27..31 -> zero pad
  }
  __syncthreads();
  // broadcast emb_d to all 128 rows of buf1 cols [256..288)
  for (int idx = tid; idx < 128 * 32; idx += THREADS) {
    const int rr = idx >> 5, cc = idx & 31;
    buf1[sidx<288, 256>(rr, 256 + cc)] = buf0[sidx<320, 320>(rr >> 6, 288 + cc)];
  }
  __syncthreads();
  // dir layer: [feat, emb_d] (buf1, K=288) -> buf0 cols [0..128)
  layer_mfma<288, 1, 288, 256, 320, 320>(buf1, 0, buf0, wp + OFF_WD, A.bd0, wave, ln15, lhi);
  __syncthreads();
  // rgb head: sigmoid(x_dir . Wrgb^T + brgb); fused float4 {dens, rgb} store
  {
    const int r = wave * 16 + ln15;
    float s0 = 0.f, s1 = 0.f, s2 = 0.f;
#pragma unroll
    for (int jj = 0; jj < 4; ++jj) {
      const bf16x8 ch = *(const bf16x8*)(buf0 + sidx<320, 320>(r, lhi * 32 + jj * 8));
#pragma unroll
      for (int e = 0; e < 8; ++e) {
        const int k = lhi * 32 + jj * 8 + e;
        const float xv = bf2f((unsigned short)ch[e]);
        s0 += xv * A.Wrgb[k];
        s1 += xv * A.Wrgb[128 + k];
        s2 += xv * A.Wrgb[256 + k];
      }
    }
    s0 += __shfl_xor(s0, 16); s0 += __shfl_xor(s0, 32);
    s1 += __shfl_xor(s1, 16); s1 += __shfl_xor(s1, 32);
    s2 += __shfl_xor(s2, 16); s2 += __shfl_xor(s2, 32);
    if (lhi == 0) {
      f32x4 o;
      o[0] = dens;
      o[1] = 1.f / (1.f + expf(-(s0 + A.brgb[0])));
      o[2] = 1.f / (1.f + expf(-(s1 + A.brgb[1])));
      o[3] = 1.f / (1.f + expf(-(s2 + A.brgb[2])));
      *(f32x4*)(A.out + (blk * MTILE + r) * 4) = o;
    }
  }
}

// ---------------- weight packing prologue (fp32 -> bf16, K padded) ----------------
struct PackDesc { const float* src; int out_dim, in_dim, kpad, dst_off; };
struct PackArgs { PackDesc d[10]; };

__global__ void __launch_bounds__(256) pack_weights(PackArgs P, unsigned short* dst) {
  const PackDesc pd = P.d[blockIdx.y];
  const int idx = blockIdx.x * 256 + threadIdx.x;
  const int tot = pd.out_dim * pd.kpad;
  if (idx >= tot) return;
  const int o = idx / pd.kpad;
  const int k = idx - o * pd.kpad;
  const float v = (k < pd.in_dim) ? pd.src[o * pd.in_dim + k] : 0.f;
  dst[pd.dst_off + idx] = f2bf(v);
}

extern "C" void kernel_launch(void* const* d_in, const int* in_sizes, int n_in,
                              void* d_out, int out_size, void* d_ws, size_t ws_size,
                              hipStream_t stream) {
  unsigned short* wpack = (unsigned short*)d_ws;

  const float* Wx[8]; const float* bx[8];
  for (int i = 0; i < 8; ++i) {
    Wx[i] = (const float*)d_in[2 + 2 * i];
    bx[i] = (const float*)d_in[3 + 2 * i];
  }

  PackArgs P;
  P.d[0] = { Wx[0], 256, 63, 64, OFF_W0 };
  P.d[1] = { Wx[1], 256, 256, 256, OFF_W1 };
  P.d[2] = { Wx[2], 256, 256, 256, OFF_W2 };
  P.d[3] = { Wx[3], 256, 256, 256, OFF_W3 };
  P.d[4] = { Wx[4], 256, 319, 320, OFF_W4 };
  P.d[5] = { Wx[5], 256, 256, 256, OFF_W5 };
  P.d[6] = { Wx[6], 256, 256, 256, OFF_W6 };
  P.d[7] = { Wx[7], 256, 256, 256, OFF_W7 };
  P.d[8] = { (const float*)d_in[22], 256, 256, 256, OFF_WF };  // Wfeat
  P.d[9] = { (const float*)d_in[18], 128, 283, 288, OFF_WD };  // Wd0
  hipLaunchKernelGGL(pack_weights, dim3(320, 10), dim3(256), 0, stream, P, wpack);

  NerfArgs A;
  A.sp = (const float*)d_in[0];
  A.dirs = (const float*)d_in[1];
  A.wp = wpack;
  A.bx0 = bx[0]; A.bx1 = bx[1]; A.bx2 = bx[2]; A.bx3 = bx[3];
  A.bx4 = bx[4]; A.bx5 = bx[5]; A.bx6 = bx[6]; A.bx7 = bx[7];
  A.bd0 = (const float*)d_in[19];
  A.Wden = (const float*)d_in[20];
  A.bden = (const float*)d_in[21];
  A.bfeat = (const float*)d_in[23];
  A.Wrgb = (const float*)d_in[24];
  A.brgb = (const float*)d_in[25];
  A.out = (float*)d_out;

  const int lds_bytes = (128 * 320 + 128 * 288) * 2;  // 155648 B
  hipFuncSetAttribute((const void*)nerf_main, hipFuncAttributeMaxDynamicSharedMemorySize, lds_bytes);
  hipLaunchKernelGGL(nerf_main, dim3(NBLK), dim3(THREADS), lds_bytes, stream, A);
}